// Round 10
// baseline (31.291 us; speedup 1.0000x reference)
//
#include <hip/hip_runtime.h>

// KAN activation: out[b,o,i] = sum_t B_t(x[b,i]) * coef[o,i,t]
// B=2048, IN=OUT=64, uniform knots, order 3, 11 basis funcs.
//
// Round-10: DISCRIMINATING EXPERIMENT (intrinsic serialization vs fixed
// per-launch overhead). Two kernels, ZERO LDS / ZERO barriers in the hot one:
//
// K1 (prep, ~2us): for all 131072 (b,i) pairs compute the dense 12-slot
//     basis vector (closed-form cubic, select-chain into registers) and
//     store as 3 float4 planes in d_ws (coalesced). Also transpose coef
//     into [o][t][i] so consumer coef loads are lane-coalesced.
// K2 (consume, memset-shaped): thread owns (i, 2 consecutive o). 22
//     coalesced coef loads once; then 16 independent rows: 3 coalesced
//     float4 loads (L2/L3-hot ws) + 22 FMA + 2 coalesced 256B stores.
//     No sync, ~50 VGPR, 4 blocks/CU resident, waves fully independent.
//
// H1 (intrinsic): total ~10-11us.  H2 (launch overhead): ~21us -> measures
// the overhead, revert to R9 single-kernel and declare floor next round.

#define BATCH    2048
#define IN_DIM   64
#define OUT_DIM  64
#define NCOEF    11
#define NPAIRS   (BATCH * IN_DIM)          // 131072
#define PLANE_F  (NPAIRS * 4)              // floats per basis plane (524288)
#define BASES_F  (3 * PLANE_F)             // 1572864 floats = 6.29 MB
#define COEFT_F  (OUT_DIM * IN_DIM * NCOEF) // 45056 floats
#define B_TILE   16

// ---------------- K1: bases + coef transpose into d_ws ----------------
__global__ __launch_bounds__(256) void kan_prep(
    const float* __restrict__ x,      // (2048, 64)
    const float* __restrict__ grid,   // uniform knots (broadcast)
    const float* __restrict__ coef,   // (64, 64, 11)
    float* __restrict__ ws)           // [bases 3 planes][coefT]
{
    const int blk = blockIdx.x;
    const int tid = threadIdx.x;

    if (blk < NPAIRS / 256) {
        // ---- dense basis vector for one (b,i) pair ----
        const int p = blk * 256 + tid;            // p = b*64 + i, coalesced
        const float xv = x[p];
        const float g0    = grid[0];
        const float inv_h = 1.0f / (grid[1] - g0);

        const float pos = (xv - g0) * inv_h;      // cell coord in [0,14)
        const float fm  = floorf(pos);
        const float t   = pos - fm;
        const int   mb  = (pos >= 0.0f && pos < 14.0f) ? ((int)fm - 3) : -1000;

        const float t2 = t * t;
        const float t3 = t2 * t;
        const float s  = 1.0f - t;
        const float w0 = s * s * s * (1.0f / 6.0f);
        const float w1 = (3.0f * t3 - 6.0f * t2 + 4.0f) * (1.0f / 6.0f);
        const float w2 = (-3.0f * t3 + 3.0f * t2 + 3.0f * t + 1.0f) * (1.0f / 6.0f);
        const float w3 = t3 * (1.0f / 6.0f);

        float dense[12];
        #pragma unroll
        for (int tt = 0; tt < 12; ++tt) {
            const int d = tt - mb;
            dense[tt] = (d == 0) ? w0 : (d == 1) ? w1 : (d == 2) ? w2
                      : (d == 3) ? w3 : 0.0f;
        }

        // 3 coalesced float4 plane stores
        #pragma unroll
        for (int pl = 0; pl < 3; ++pl) {
            float4 v = make_float4(dense[pl * 4 + 0], dense[pl * 4 + 1],
                                   dense[pl * 4 + 2], dense[pl * 4 + 3]);
            *(float4*)&ws[pl * PLANE_F + p * 4] = v;
        }
    } else {
        // ---- coef transpose: [o][i][t] -> [o][t][i] ----
        // 16 blocks x 256 threads x 11 iters = 45056 elements exactly
        float* ct = ws + BASES_F;
        const int base = (blk - NPAIRS / 256) * 256 + tid;   // 0..4095
        #pragma unroll
        for (int k = 0; k < NCOEF; ++k) {
            const int idx = base + k * 4096;                 // < 45056
            const int o = idx / (IN_DIM * NCOEF);
            const int r = idx - o * (IN_DIM * NCOEF);
            const int i = r / NCOEF;
            const int t = r - i * NCOEF;
            ct[(o * NCOEF + t) * IN_DIM + i] = coef[idx];    // read coalesced
        }
    }
}

// ---------------- K2: barrier-free streaming consumer ----------------
__global__ __launch_bounds__(256) void kan_main(
    const float* __restrict__ ws,
    float* __restrict__ out)          // (2048, 64, 64)
{
    const float* bases = ws;
    const float* ct    = ws + BASES_F;

    const int tid = threadIdx.x;
    const int ot  = blockIdx.x & 7;            // 8 o-tiles of 8
    const int b0  = (blockIdx.x >> 3) * B_TILE;

    const int i   = tid & 63;                  // lane = i -> coalesced
    const int grp = tid >> 6;                  // 0..3
    const int o   = ot * 8 + grp * 2;

    // 22 coef regs via coalesced loads from the transposed layout
    float c[2][NCOEF];
    #pragma unroll
    for (int oo = 0; oo < 2; ++oo)
        #pragma unroll
        for (int t = 0; t < NCOEF; ++t)
            c[oo][t] = ct[((o + oo) * NCOEF + t) * IN_DIM + i];

    // 16 independent rows: load bases -> 22 FMA -> 2 coalesced stores
    #pragma unroll 4
    for (int rr = 0; rr < B_TILE; ++rr) {
        const int p = (b0 + rr) * IN_DIM + i;
        const float4 v0 = *(const float4*)&bases[0 * PLANE_F + p * 4];
        const float4 v1 = *(const float4*)&bases[1 * PLANE_F + p * 4];
        const float4 v2 = *(const float4*)&bases[2 * PLANE_F + p * 4];

        float* op = &out[(size_t)(b0 + rr) * (OUT_DIM * IN_DIM) + o * IN_DIM + i];
        #pragma unroll
        for (int oo = 0; oo < 2; ++oo) {
            float acc;
            acc  = v0.x * c[oo][0] + v0.y * c[oo][1] + v0.z * c[oo][2] + v0.w * c[oo][3];
            acc += v1.x * c[oo][4] + v1.y * c[oo][5] + v1.z * c[oo][6] + v1.w * c[oo][7];
            acc += v2.x * c[oo][8] + v2.y * c[oo][9] + v2.z * c[oo][10];
            op[oo * IN_DIM] = acc;
        }
    }
}

extern "C" void kernel_launch(void* const* d_in, const int* in_sizes, int n_in,
                              void* d_out, int out_size, void* d_ws, size_t ws_size,
                              hipStream_t stream) {
    const float* x    = (const float*)d_in[0];
    const float* grid = (const float*)d_in[1];
    const float* coef = (const float*)d_in[2];
    float* out = (float*)d_out;
    float* ws  = (float*)d_ws;   // needs 6.47 MB; harness provides far more

    kan_prep<<<NPAIRS / 256 + 16, 256, 0, stream>>>(x, grid, coef, ws);
    kan_main<<<(BATCH / B_TILE) * 8, 256, 0, stream>>>(ws, out);
}

// Round 11
// 14.026 us; speedup vs baseline: 2.2309x; 2.2309x over previous
//
#include <hip/hip_runtime.h>

// KAN activation: out[b,o,i] = sum_t B_t(x[b,i]) * coef[o,i,t]
// B=2048, IN=OUT=64, uniform knots (15), order k=3, 11 basis funcs.
//
// FINAL structure (round-9, best = 14.4us):
//   ONE kernel, ONE barrier, ONE block generation per CU.
//   grid = 256 blocks (1/CU), block = 1024 threads (16 waves = 4/SIMD)
//   per block: 16 batch rows x 32 output dims
//   LDS 136 KB = coef half (32ox64ix11 = 88 KB, coalesced stride-1 stage)
//              + bases (16 rows x 64 i x 12 slots = 48 KB, float4 planes).
//   After the barrier each thread streams 16 independent rows
//   (3x ds_read_b128 + 22 FMA + 2x 256B coalesced stores), fully unrolled.
//
// Measured decomposition (rounds 2-10 evidence chain):
//   store floor 33.5MB @ 6.3TB/s ~ 5.3us  +  startup ~1.5us
//   + fixed per-launch overhead ~7.5-9us (confirmed by round-10 two-kernel
//     experiment: +1 dependent launch cost +17us >> its ~3us of work)
//   = ~14.4us. The overhead term is outside kernel control -> roofline.

#define BATCH    2048
#define IN_DIM   64
#define OUT_DIM  64
#define NCOEF    11
#define B_TILE   16
#define O_HALF   32
#define NPAIR    (B_TILE * IN_DIM)           // 1024 (1 pair/thread)
#define PLANE    (NPAIR * 4)                 // floats per basis plane
#define CTILE    (O_HALF * IN_DIM * NCOEF)   // 22528 floats = 88 KiB

__global__ __launch_bounds__(1024) void kan_kernel(
    const float* __restrict__ x,     // (2048, 64)
    const float* __restrict__ grid,  // (64, 64, 15) broadcast uniform knots
    const float* __restrict__ coef,  // (64, 64, 11)
    float* __restrict__ out)         // (2048, 64, 64)
{
    __shared__ float coef_lds[CTILE];      // 88 KiB
    __shared__ float bas_lds[3 * PLANE];   // 48 KiB

    const int tid    = threadIdx.x;
    const int o_half = blockIdx.x & 1;
    const int b0     = (blockIdx.x >> 1) * B_TILE;

    // ---- x load first (bases depend on it) ----
    const int p = tid;                        // p = rr*64 + ii
    const float xv = x[(size_t)(b0 + (p >> 6)) * IN_DIM + (p & 63)];

    // ---- coef half-tile -> LDS: coalesced stride-1 copy (22/thread) ----
    const float* csrc = coef + (size_t)o_half * CTILE;
    #pragma unroll
    for (int q = 0; q < CTILE / 1024; ++q)
        coef_lds[tid + q * 1024] = csrc[tid + q * 1024];

    const float g0    = grid[0];
    const float inv_h = 1.0f / (grid[1] - g0);

    // ---- bases: closed-form cubic weights, 1 (b,i) pair per thread ----
    {
        const float4 z = make_float4(0.f, 0.f, 0.f, 0.f);
        *(float4*)&bas_lds[0 * PLANE + p * 4] = z;
        *(float4*)&bas_lds[1 * PLANE + p * 4] = z;
        *(float4*)&bas_lds[2 * PLANE + p * 4] = z;

        const float pos = (xv - g0) * inv_h;   // cell coord in [0,14)
        if (pos >= 0.0f && pos < 14.0f) {
            const int   m  = (int)pos;
            const float t  = pos - (float)m;
            const float t2 = t * t;
            const float t3 = t2 * t;
            const float s  = 1.0f - t;
            const float w0 = s * s * s * (1.0f / 6.0f);
            const float w1 = (3.0f * t3 - 6.0f * t2 + 4.0f) * (1.0f / 6.0f);
            const float w2 = (-3.0f * t3 + 3.0f * t2 + 3.0f * t + 1.0f) * (1.0f / 6.0f);
            const float w3 = t3 * (1.0f / 6.0f);

            const int mb = m - 3;
            int idx;
            idx = mb + 0; if ((unsigned)idx < NCOEF) bas_lds[(idx >> 2) * PLANE + p * 4 + (idx & 3)] = w0;
            idx = mb + 1; if ((unsigned)idx < NCOEF) bas_lds[(idx >> 2) * PLANE + p * 4 + (idx & 3)] = w1;
            idx = mb + 2; if ((unsigned)idx < NCOEF) bas_lds[(idx >> 2) * PLANE + p * 4 + (idx & 3)] = w2;
            idx = mb + 3; if ((unsigned)idx < NCOEF) bas_lds[(idx >> 2) * PLANE + p * 4 + (idx & 3)] = w3;
        }
    }
    __syncthreads();   // the ONLY barrier

    // ---- coef regs: 22 from LDS (lane word-stride 11 = odd -> free) ----
    const int i   = tid & 63;
    const int grp = tid >> 6;                  // 0..15
    const int ol0 = grp * 2;                   // local o within the half
    const int o   = o_half * O_HALF + ol0;

    float c[2][NCOEF];
    #pragma unroll
    for (int oo = 0; oo < 2; ++oo) {
        const int row = ((ol0 + oo) * IN_DIM + i) * NCOEF;
        #pragma unroll
        for (int t = 0; t < NCOEF; ++t)
            c[oo][t] = coef_lds[row + t];
    }

    // ---- stream 16 independent rows: no sync, fully unrolled ----
    float* op0 = &out[(size_t)b0 * (OUT_DIM * IN_DIM) + o * IN_DIM + i];
    #pragma unroll
    for (int rr = 0; rr < B_TILE; ++rr) {
        const int pp = rr * IN_DIM + i;
        const float4 v0 = *(const float4*)&bas_lds[0 * PLANE + pp * 4];
        const float4 v1 = *(const float4*)&bas_lds[1 * PLANE + pp * 4];
        const float4 v2 = *(const float4*)&bas_lds[2 * PLANE + pp * 4];

        float* op = op0 + (size_t)rr * (OUT_DIM * IN_DIM);
        #pragma unroll
        for (int oo = 0; oo < 2; ++oo) {
            float acc;
            acc  = v0.x * c[oo][0] + v0.y * c[oo][1] + v0.z * c[oo][2] + v0.w * c[oo][3];
            acc += v1.x * c[oo][4] + v1.y * c[oo][5] + v1.z * c[oo][6] + v1.w * c[oo][7];
            acc += v2.x * c[oo][8] + v2.y * c[oo][9] + v2.z * c[oo][10];
            op[oo * IN_DIM] = acc;
        }
    }
}

extern "C" void kernel_launch(void* const* d_in, const int* in_sizes, int n_in,
                              void* d_out, int out_size, void* d_ws, size_t ws_size,
                              hipStream_t stream) {
    const float* x    = (const float*)d_in[0];
    const float* grid = (const float*)d_in[1];
    const float* coef = (const float*)d_in[2];
    float* out = (float*)d_out;

    const int nblocks = (BATCH / B_TILE) * 2;   // 256 = 1 block/CU
    kan_kernel<<<nblocks, 1024, 0, stream>>>(x, grid, coef, out);
}